// Round 17
// baseline (90.576 us; speedup 1.0000x reference)
//
#include <hip/hip_runtime.h>

// VQEmbedding: x [N=32768, D=256] fp32, embedding [M=1024, D=256] fp32.
// Outputs (flat fp32): quantized [N*D], loss [1], indices [N] (as float), perplexity [1].
// R17: counted-vmcnt ring at the R14 MFMA shape. 512-thr blocks (8 waves = 4 rpairs
// x 2 mhalf), grid 256 (1 block/CU); ring-3 16KB-per-half units; per unit:
// vmcnt(4) + raw s_barrier (NO vmcnt(0) drain in loop), stage(g+2) after barrier.
// Wave = 32 x-rows (32x32x16 B-operand) x 512 embs; 3 indep MFMA chains.
// dist = ||e||^2 - 2 x.e ; loss = 1.25*(sum bestdist + ||x||_F^2)/(N*D).

constexpr int D = 256;
constexpr int M = 1024;
constexpr int ROWS = 128;   // x rows per block (32 per wave, rpair-shared)

typedef _Float16 f16;
typedef __attribute__((ext_vector_type(8)))  _Float16 f16x8;
typedef __attribute__((ext_vector_type(4)))  float f32x4;
typedef __attribute__((ext_vector_type(16))) float f32x16;

// ws layout (bytes):
//   [0..4)        loss accumulator (float)
//   [4..4100)     counts (1024 floats, float-idx 1..1025)
//   [4112..8208)  enorm (1024 floats, float-idx 1028..2052)
//   [8320..1056896)  e split-f16 table, A-frag order for mfma_32x32x16_f16:
//     16B elem v: lane=v&63, u=(v>>6)&15, ksl=(v>>10)&1, t32=v>>11;
//     kstep=u&7, spl=u>>3 (0=hi,1=lo);
//     content = split(e[t32*32+(lane&31)][(ksl*8+kstep)*16+(lane>>5)*8 .. +8]).
constexpr size_t WS_ENORM_F = 1028;
constexpr size_t WS_TAB_B   = 8320;
constexpr size_t WS_NEEDED  = 1056896;

__device__ inline void gload_lds16(const void* g, void* l) {
    __builtin_amdgcn_global_load_lds(
        (const __attribute__((address_space(1))) unsigned int*)(g),
        (__attribute__((address_space(3))) unsigned int*)(l), 16, 0, 0);
}

// ---------------- prep: A-frag-ordered split-f16 e table + ||e||^2 + ws zero ----------------
__global__ __launch_bounds__(256) void prep_kernel(const float* __restrict__ e,
                                                   float* __restrict__ ws) {
    const int b = blockIdx.x, t = threadIdx.x;
    if (b < 256) {
        int v    = b * 256 + t;               // 16B element index
        int lane = v & 63, u = (v >> 6) & 15;
        int ksl  = (v >> 10) & 1, t32 = v >> 11;
        int kstep = u & 7, spl = u >> 3;
        int row  = t32 * 32 + (lane & 31);
        int col0 = (ksl * 8 + kstep) * 16 + (lane >> 5) * 8;
        const float* p = e + (size_t)row * D + col0;
        f32x4 a = *reinterpret_cast<const f32x4*>(p);
        f32x4 c = *reinterpret_cast<const f32x4*>(p + 4);
        f16 h0=(f16)a.x,h1=(f16)a.y,h2=(f16)a.z,h3=(f16)a.w;
        f16 h4=(f16)c.x,h5=(f16)c.y,h6=(f16)c.z,h7=(f16)c.w;
        f16x8 out;
        if (spl == 0) out = (f16x8){h0,h1,h2,h3,h4,h5,h6,h7};
        else          out = (f16x8){(f16)(a.x-(float)h0),(f16)(a.y-(float)h1),
                                    (f16)(a.z-(float)h2),(f16)(a.w-(float)h3),
                                    (f16)(c.x-(float)h4),(f16)(c.y-(float)h5),
                                    (f16)(c.z-(float)h6),(f16)(c.w-(float)h7)};
        *reinterpret_cast<f16x8*>((char*)ws + WS_TAB_B + (size_t)v * 16) = out;
    } else if (b < 512) {
        int row  = (b - 256) * 4 + (t >> 6);  // 1024 rows over blocks 256..511
        int lane = t & 63;
        f32x4 a = *reinterpret_cast<const f32x4*>(e + (size_t)row * D + lane * 4);
        float s = fmaf(a.x, a.x, fmaf(a.y, a.y, fmaf(a.z, a.z, a.w * a.w)));
#pragma unroll
        for (int o = 32; o > 0; o >>= 1) s += __shfl_down(s, o, 64);
        if (lane == 0) ws[WS_ENORM_F + row] = s;
    } else {
        for (int i = t; i < 1026; i += 256) ws[i] = 0.f;   // loss + counts
    }
}

// ---------------- fused main kernel: 8 waves, ring-3, counted vmcnt ----------------
__global__ __launch_bounds__(512, 1) void vq_fused_kernel(
    const float* __restrict__ x, const float* __restrict__ e,
    float* __restrict__ outQ, float* __restrict__ outIdx, float* __restrict__ ws)
{
    __shared__ ushort ebuf[3][2][8192]; // ring-3 x [mhalf] x 16KB A-frag region
    __shared__ float  en_s[M];          // 4 KB
    __shared__ float  wval[8][32];
    __shared__ int    widx[8][32];
    __shared__ float  xns[ROWS];
    __shared__ int    fidx[ROWS];

    const int tid   = threadIdx.x;
    const int w     = __builtin_amdgcn_readfirstlane(tid >> 6);  // wave 0..7
    const int l     = tid & 63;
    const int rpair = w >> 1;            // row group: rows R + rpair*32 + (l&31)
    const int mhalf = w & 1;             // codebook half: embs [mhalf*512, +512)
    const int R     = blockIdx.x * ROWS;
    const int xr    = l & 31;            // this lane's x-row (B col)
    const int kg    = l >> 5;            // k-group (0/1) within 16-wide k blocks
    const char* tab = (const char*)ws + WS_TAB_B;

    // stage unit g=(tt,ks): 32 segs of 1KB (16 per half); wave w stages segs w*4..+3
    auto stage = [&](int buf, int g) {
        int tt = g >> 1, ks = g & 1;
#pragma unroll
        for (int i = 0; i < 4; ++i) {
            int S = w * 4 + i, half = S >> 4, sg = S & 15;
            gload_lds16(tab + (size_t)(((half * 16 + tt) * 2 + ks)) * 16384 + sg * 1024 + l * 16,
                        &ebuf[buf][half][sg * 512]);
        }
    };

    // enorm -> LDS (first 256 threads)
    if (tid < 256) {
        f32x4 v = *reinterpret_cast<const f32x4*>(ws + WS_ENORM_F + tid * 4);
        *reinterpret_cast<f32x4*>(&en_s[tid * 4]) = v;
    }

    // x rows -> split-f16 B-frags: lane l holds x[R+rpair*32+xr][ku*16 + kg*8 .. +8]
    f16x8 Xh[16], Xl[16];
    float xn;
    {
        float s = 0.f;
#pragma unroll
        for (int ku = 0; ku < 16; ++ku) {
            const float* p = x + (size_t)(R + rpair * 32 + xr) * D + ku * 16 + kg * 8;
            f32x4 a = *reinterpret_cast<const f32x4*>(p);
            f32x4 c = *reinterpret_cast<const f32x4*>(p + 4);
            f16 h0=(f16)a.x,h1=(f16)a.y,h2=(f16)a.z,h3=(f16)a.w;
            f16 h4=(f16)c.x,h5=(f16)c.y,h6=(f16)c.z,h7=(f16)c.w;
            Xh[ku] = (f16x8){h0,h1,h2,h3,h4,h5,h6,h7};
            Xl[ku] = (f16x8){(f16)(a.x-(float)h0),(f16)(a.y-(float)h1),
                             (f16)(a.z-(float)h2),(f16)(a.w-(float)h3),
                             (f16)(c.x-(float)h4),(f16)(c.y-(float)h5),
                             (f16)(c.z-(float)h6),(f16)(c.w-(float)h7)};
            s = fmaf(a.x,a.x,fmaf(a.y,a.y,fmaf(a.z,a.z,fmaf(a.w,a.w,
                fmaf(c.x,c.x,fmaf(c.y,c.y,fmaf(c.z,c.z,fmaf(c.w,c.w,s))))))));
        }
        s += __shfl_xor(s, 32, 64);      // partner lane covers the other k-half
        xn = s;
    }

    // prologue: all x/enorm vmem retired (consumed above); only stage loads count
    __builtin_amdgcn_sched_barrier(0);
    stage(0, 0);
    stage(1, 1);
    asm volatile("s_waitcnt lgkmcnt(0)" ::: "memory");  // en_s ds_writes drained

    float bV = 3.4e38f;
    int   bI = 0;
    f32x16 accA, accB, accC;
    int cb = 0;                          // g % 3

    for (int g = 0; g < 32; ++g) {       // 32 units (16 emb-tiles x 2 K-slices)
        // own unit-g loads landed (unit g+1's 4 may stay in flight across barrier)
        if (g < 31) asm volatile("s_waitcnt vmcnt(4)" ::: "memory");
        else        asm volatile("s_waitcnt vmcnt(0)" ::: "memory");
        __builtin_amdgcn_s_barrier();    // all waves' unit-g loads landed

        if (g + 2 < 32) {                // slot (g+2)%3 = slot of unit g-1 (readers done)
            int pb = cb + 2; if (pb >= 3) pb -= 3;
            stage(pb, g + 2);
        }

        const ushort* eb = &ebuf[cb][mhalf][0];
        if ((g & 1) == 0) {              // ks=0: reset chains, consume Xh/Xl[0..7]
            accA = (f32x16){0.f}; accB = (f32x16){0.f}; accC = (f32x16){0.f};
            __builtin_amdgcn_s_setprio(1);
#pragma unroll
            for (int kstep = 0; kstep < 8; ++kstep) {
                f16x8 Ah = *reinterpret_cast<const f16x8*>(eb + kstep * 512 + l * 8);
                f16x8 Al = *reinterpret_cast<const f16x8*>(eb + (8 + kstep) * 512 + l * 8);
                accA = __builtin_amdgcn_mfma_f32_32x32x16_f16(Ah, Xh[kstep], accA, 0, 0, 0);
                accB = __builtin_amdgcn_mfma_f32_32x32x16_f16(Al, Xh[kstep], accB, 0, 0, 0);
                accC = __builtin_amdgcn_mfma_f32_32x32x16_f16(Ah, Xl[kstep], accC, 0, 0, 0);
            }
            __builtin_amdgcn_s_setprio(0);
        } else {                         // ks=1: consume Xh/Xl[8..15], then fold tile
            __builtin_amdgcn_s_setprio(1);
#pragma unroll
            for (int kstep = 0; kstep < 8; ++kstep) {
                f16x8 Ah = *reinterpret_cast<const f16x8*>(eb + kstep * 512 + l * 8);
                f16x8 Al = *reinterpret_cast<const f16x8*>(eb + (8 + kstep) * 512 + l * 8);
                accA = __builtin_amdgcn_mfma_f32_32x32x16_f16(Ah, Xh[8 + kstep], accA, 0, 0, 0);
                accB = __builtin_amdgcn_mfma_f32_32x32x16_f16(Al, Xh[8 + kstep], accB, 0, 0, 0);
                accC = __builtin_amdgcn_mfma_f32_32x32x16_f16(Ah, Xl[8 + kstep], accC, 0, 0, 0);
            }
            __builtin_amdgcn_s_setprio(0);

            // fold: C/D col=lane&31 (x-row), row=(reg&3)+8*(reg>>2)+4*kg
            const int mbase = mhalf * 512 + (g >> 1) * 32;
#pragma unroll
            for (int rq = 0; rq < 4; ++rq) {
                f32x4 en4 = *reinterpret_cast<const f32x4*>(&en_s[mbase + rq * 8 + kg * 4]);
#pragma unroll
                for (int j = 0; j < 4; ++j) {
                    int reg = rq * 4 + j;
                    int mi  = mbase + rq * 8 + kg * 4 + j;
                    float dv = fmaf(-2.f, accA[reg] + accB[reg] + accC[reg], en4[j]);
                    if (dv < bV) { bV = dv; bI = mi; }
                }
            }
        }
        cb = cb + 1; if (cb >= 3) cb -= 3;
    }

    // reduce lane <-> lane^32 (same x-row, disjoint emb sets), tie -> lower idx
    {
        float ov = __shfl_xor(bV, 32, 64);
        int   oi = __shfl_xor(bI, 32, 64);
        if (ov < bV || (ov == bV && oi < bI)) { bV = ov; bI = oi; }
    }
    if (l < 32) {                        // publish per-wave candidates
        wval[w][xr] = bV;
        widx[w][xr] = bI;
        if (mhalf == 0) xns[rpair * 32 + xr] = xn;
    }
    __syncthreads();

    // pair merge: half-A idx (<512) < half-B idx -> strict < keeps lowest-index tie
    if (tid < ROWS) {
        int r = tid, g2 = r >> 5, rr = r & 31;
        float v0 = wval[g2 * 2 + 0][rr]; int i0 = widx[g2 * 2 + 0][rr];
        float v1 = wval[g2 * 2 + 1][rr]; int i1 = widx[g2 * 2 + 1][rr];
        float fv; int fi;
        if (v1 < v0) { fv = v1; fi = i1; } else { fv = v0; fi = i0; }
        fidx[r] = fi;
        outIdx[R + r] = (float)fi;
        atomicAdd(ws + 1 + fi, 1.0f);
        float ls = fv + xns[r];
#pragma unroll
        for (int o = 32; o > 0; o >>= 1) ls += __shfl_down(ls, o, 64);
        if ((r & 63) == 0) atomicAdd(ws, ls);
    }
    __syncthreads();

    // fused gather: quantized = embedding[idx] (exact fp32), nontemporal store
#pragma unroll
    for (int it = 0; it < 16; ++it) {
        int u = it * 512 + tid;
        int row = u >> 6, c4 = u & 63;   // 128 rows x 64 f32x4 units
        f32x4 v = *reinterpret_cast<const f32x4*>(e + (size_t)fidx[row] * D + c4 * 4);
        __builtin_nontemporal_store(v, reinterpret_cast<f32x4*>(outQ + (size_t)(R + row) * D + c4 * 4));
    }
}

// ---------------- fallback fp32 path (only if ws too small) ----------------
__global__ void enorm_kernel(const float* __restrict__ e, float* __restrict__ enorm) {
    int m = blockIdx.x, l = threadIdx.x;
    const f32x4 v = *reinterpret_cast<const f32x4*>(e + m * D + l * 4);
    float s = fmaf(v.x, v.x, fmaf(v.y, v.y, fmaf(v.z, v.z, v.w * v.w)));
#pragma unroll
    for (int o = 32; o > 0; o >>= 1) s += __shfl_down(s, o, 64);
    if (l == 0) enorm[m] = s;
}

__global__ __launch_bounds__(256, 2) void vq_main_kernel(
    const float* __restrict__ x, const float* __restrict__ e,
    float* __restrict__ outQ, float* __restrict__ outIdx, float* __restrict__ ws) {
    __shared__ f32x4 xs[64][64];
    __shared__ float cval[4][64];
    __shared__ int   cidx[4][64];
    __shared__ int   fidx[64];
    const int tid = threadIdx.x, row0 = blockIdx.x * 64;
#pragma unroll
    for (int it = 0; it < 16; ++it) {
        int f = it * 256 + tid, rr = f >> 6, c4 = f & 63;
        xs[rr][c4 ^ (rr & 7)] = *reinterpret_cast<const f32x4*>(x + (row0 + rr) * D + c4 * 4);
    }
    __syncthreads();
    const int r = tid & 63, c = __builtin_amdgcn_readfirstlane(tid >> 6), sw = r & 7;
    float xnorm = 0.f;
    if (c == 0) {
        f32x4 a = (f32x4){0.f,0.f,0.f,0.f};
        for (int d4 = 0; d4 < 64; ++d4) {
            f32x4 xv = xs[r][d4 ^ sw];
            a.x = fmaf(xv.x, xv.x, a.x); a.y = fmaf(xv.y, xv.y, a.y);
            a.z = fmaf(xv.z, xv.z, a.z); a.w = fmaf(xv.w, xv.w, a.w);
        }
        xnorm = (a.x + a.y) + (a.z + a.w);
    }
    const float* __restrict__ enorm = ws + WS_ENORM_F;
    float bestVal = 3.4e38f; int bestIdx = 0;
    for (int chunk = 0; chunk < M / 32; ++chunk) {
        const int m0 = chunk * 32 + c * 8;
        f32x4 acc[8];
#pragma unroll
        for (int mi = 0; mi < 8; ++mi) acc[mi] = (f32x4){0.f,0.f,0.f,0.f};
#pragma unroll 2
        for (int d4 = 0; d4 < 64; ++d4) {
            const f32x4 xv = xs[r][d4 ^ sw];
#pragma unroll
            for (int mi = 0; mi < 8; ++mi) {
                const f32x4 ev = *reinterpret_cast<const f32x4*>(e + (m0 + mi) * D + d4 * 4);
                acc[mi].x = fmaf(xv.x, ev.x, acc[mi].x); acc[mi].y = fmaf(xv.y, ev.y, acc[mi].y);
                acc[mi].z = fmaf(xv.z, ev.z, acc[mi].z); acc[mi].w = fmaf(xv.w, ev.w, acc[mi].w);
            }
        }
#pragma unroll
        for (int mi = 0; mi < 8; ++mi) {
            float dot = (acc[mi].x + acc[mi].y) + (acc[mi].z + acc[mi].w);
            float val = enorm[m0 + mi] - 2.0f * dot;
            if (val < bestVal) { bestVal = val; bestIdx = m0 + mi; }
        }
    }
    cval[c][r] = bestVal; cidx[c][r] = bestIdx;
    __syncthreads();
    if (c == 0) {
        float bv = bestVal; int bi = bestIdx;
#pragma unroll
        for (int cc = 1; cc < 4; ++cc) {
            float v = cval[cc][r]; int i = cidx[cc][r];
            if (v < bv || (v == bv && i < bi)) { bv = v; bi = i; }
        }
        fidx[r] = bi; outIdx[row0 + r] = (float)bi;
        atomicAdd(ws + 1 + bi, 1.0f);
        float dist = bv + xnorm;
#pragma unroll
        for (int o = 32; o > 0; o >>= 1) dist += __shfl_down(dist, o, 64);
        if (r == 0) atomicAdd(ws, dist);
    }
    __syncthreads();
#pragma unroll
    for (int it = 0; it < 16; ++it) {
        int f = it * 256 + tid, rr = f >> 6, c4 = f & 63;
        *reinterpret_cast<f32x4*>(outQ + (row0 + rr) * D + c4 * 4) =
            *reinterpret_cast<const f32x4*>(e + fidx[rr] * D + c4 * 4);
    }
}

// ---------------- finalize: loss + perplexity ----------------
__global__ void vq_final_kernel(const float* __restrict__ ws,
                                float* __restrict__ outLoss, float* __restrict__ outPpl,
                                float invN, float invND) {
    int t = threadIdx.x;
    float p = ws[1 + t] * invN;
    float term = p * logf(p + 1e-10f);
#pragma unroll
    for (int o = 32; o > 0; o >>= 1) term += __shfl_down(term, o, 64);
    __shared__ float s[16];
    if ((t & 63) == 0) s[t >> 6] = term;
    __syncthreads();
    if (t == 0) {
        float tot = 0.f;
#pragma unroll
        for (int i = 0; i < 16; ++i) tot += s[i];
        *outPpl  = expf(-tot);
        *outLoss = 1.25f * ws[0] * invND;
    }
}

extern "C" void kernel_launch(void* const* d_in, const int* in_sizes, int n_in,
                              void* d_out, int out_size, void* d_ws, size_t ws_size,
                              hipStream_t stream) {
    const float* x = (const float*)d_in[0];
    const float* e = (const float*)d_in[1];
    const int NX = in_sizes[0];     // N*D = 8388608
    const int N  = NX / D;          // 32768

    float* out     = (float*)d_out;
    float* outQ    = out;
    float* outLoss = out + NX;
    float* outIdx  = out + NX + 1;
    float* outPpl  = out + NX + 1 + N;
    float* ws      = (float*)d_ws;

    if (ws_size >= WS_NEEDED && (N % ROWS) == 0) {
        prep_kernel<<<513, 256, 0, stream>>>(e, ws);   // block 512 zeroes loss+counts
        vq_fused_kernel<<<N / ROWS, 512, 0, stream>>>(x, e, outQ, outIdx, ws);
    } else {
        (void)hipMemsetAsync(d_ws, 0, 4112, stream);
        enorm_kernel<<<M, 64, 0, stream>>>(e, ws + WS_ENORM_F);
        vq_main_kernel<<<N / 64, 256, 0, stream>>>(x, e, outQ, outIdx, ws);
    }
    vq_final_kernel<<<1, 1024, 0, stream>>>(ws, outLoss, outPpl,
                                            1.0f / (float)N, 1.0f / (float)NX);
}

// Round 18
// 87.780 us; speedup vs baseline: 1.0319x; 1.0319x over previous
//
#include <hip/hip_runtime.h>

// VQEmbedding: x [N=32768, D=256] fp32, embedding [M=1024, D=256] fp32.
// Outputs (flat fp32): quantized [N*D], loss [1], indices [N] (as float), perplexity [1].
// R18: R16 base (64 rows/block, 4 waves M-split, 32x32x16, 2 blocks/CU, plain
// __syncthreads) + per-block ROTATED unit schedule (co-resident blocks stage
// disjoint table regions -> no L2 convoy; explicit idx tie-break in fold) and
// setprio REMOVED (m190: harmful in lockstep structures).
// dist = ||e||^2 - 2 x.e ; loss = 1.25*(sum bestdist + ||x||_F^2)/(N*D).

constexpr int D = 256;
constexpr int M = 1024;
constexpr int ROWS = 64;    // x rows per block (32 per wave, pair-shared)

typedef _Float16 f16;
typedef __attribute__((ext_vector_type(8)))  _Float16 f16x8;
typedef __attribute__((ext_vector_type(4)))  float f32x4;
typedef __attribute__((ext_vector_type(16))) float f32x16;

// ws layout (bytes):
//   [0..4)        loss accumulator (float)
//   [4..4100)     counts (1024 floats, float-idx 1..1025)
//   [4112..8208)  enorm (1024 floats, float-idx 1028..2052)
//   [8320..1056896)  e split-f16 table, A-frag order for mfma_32x32x16_f16:
//     16B elem v: lane=v&63, u=(v>>6)&15, ksl=(v>>10)&1, t32=v>>11;
//     kstep=u&7, spl=u>>3 (0=hi,1=lo);
//     content = split(e[t32*32+(lane&31)][(ksl*8+kstep)*16+(lane>>5)*8 .. +8]).
constexpr size_t WS_ENORM_F = 1028;
constexpr size_t WS_TAB_B   = 8320;
constexpr size_t WS_NEEDED  = 1056896;

__device__ inline void gload_lds16(const void* g, void* l) {
    __builtin_amdgcn_global_load_lds(
        (const __attribute__((address_space(1))) unsigned int*)(g),
        (__attribute__((address_space(3))) unsigned int*)(l), 16, 0, 0);
}

// ---------------- prep: A-frag-ordered split-f16 e table + ||e||^2 + ws zero ----------------
__global__ __launch_bounds__(256) void prep_kernel(const float* __restrict__ e,
                                                   float* __restrict__ ws) {
    const int b = blockIdx.x, t = threadIdx.x;
    if (b < 256) {
        int v    = b * 256 + t;               // 16B element index
        int lane = v & 63, u = (v >> 6) & 15;
        int ksl  = (v >> 10) & 1, t32 = v >> 11;
        int kstep = u & 7, spl = u >> 3;
        int row  = t32 * 32 + (lane & 31);
        int col0 = (ksl * 8 + kstep) * 16 + (lane >> 5) * 8;
        const float* p = e + (size_t)row * D + col0;
        f32x4 a = *reinterpret_cast<const f32x4*>(p);
        f32x4 c = *reinterpret_cast<const f32x4*>(p + 4);
        f16 h0=(f16)a.x,h1=(f16)a.y,h2=(f16)a.z,h3=(f16)a.w;
        f16 h4=(f16)c.x,h5=(f16)c.y,h6=(f16)c.z,h7=(f16)c.w;
        f16x8 out;
        if (spl == 0) out = (f16x8){h0,h1,h2,h3,h4,h5,h6,h7};
        else          out = (f16x8){(f16)(a.x-(float)h0),(f16)(a.y-(float)h1),
                                    (f16)(a.z-(float)h2),(f16)(a.w-(float)h3),
                                    (f16)(c.x-(float)h4),(f16)(c.y-(float)h5),
                                    (f16)(c.z-(float)h6),(f16)(c.w-(float)h7)};
        *reinterpret_cast<f16x8*>((char*)ws + WS_TAB_B + (size_t)v * 16) = out;
    } else if (b < 512) {
        int row  = (b - 256) * 4 + (t >> 6);  // 1024 rows over blocks 256..511
        int lane = t & 63;
        f32x4 a = *reinterpret_cast<const f32x4*>(e + (size_t)row * D + lane * 4);
        float s = fmaf(a.x, a.x, fmaf(a.y, a.y, fmaf(a.z, a.z, a.w * a.w)));
#pragma unroll
        for (int o = 32; o > 0; o >>= 1) s += __shfl_down(s, o, 64);
        if (lane == 0) ws[WS_ENORM_F + row] = s;
    } else {
        for (int i = t; i < 1026; i += 256) ws[i] = 0.f;   // loss + counts
    }
}

// ---------------- fused main kernel: M-split waves, rotated schedule ----------------
__global__ __launch_bounds__(256, 2) void vq_fused_kernel(
    const float* __restrict__ x, const float* __restrict__ e,
    float* __restrict__ outQ, float* __restrict__ outIdx, float* __restrict__ ws)
{
    __shared__ ushort ebuf[2][2][8192]; // [buf][mhalf][16KB A-frag region]
    __shared__ float  en_s[M];          // 4 KB
    __shared__ float  wval[4][32];
    __shared__ int    widx[4][32];
    __shared__ float  xns[ROWS];
    __shared__ int    fidx[ROWS];

    const int tid   = threadIdx.x;
    const int w     = __builtin_amdgcn_readfirstlane(tid >> 6);  // wave 0..3
    const int l     = tid & 63;
    const int rpair = w >> 1;            // row group: rows R + rpair*32 + (l&31)
    const int mhalf = w & 1;             // codebook half: embs [mhalf*512, +512)
    const int R     = blockIdx.x * ROWS;
    const int xr    = l & 31;            // this lane's x-row (B col)
    const int kg    = l >> 5;            // k-group (0/1) within 16-wide k blocks
    // schedule rotation: co-resident blocks (differing in low or mid bits) get
    // different 8-tile offsets -> stage disjoint table regions each phase
    const int r8    = 8 * (((blockIdx.x >> 8) ^ blockIdx.x) & 1);
    const char* tab = (const char*)ws + WS_TAB_B;

    auto stage = [&](int buf, int g) {
        int tt = g >> 1, ks = g & 1;
#pragma unroll
        for (int i = 0; i < 4; ++i) {
            int S = w * 4 + i, half = S >> 3, sg = (S & 7) * 2;   // 2 segs per iter
            gload_lds16(tab + (size_t)(((half * 16 + tt) * 2 + ks)) * 16384 + sg * 1024 + l * 16,
                        &ebuf[buf][half][sg * 512]);
            gload_lds16(tab + (size_t)(((half * 16 + tt) * 2 + ks)) * 16384 + (sg + 1) * 1024 + l * 16,
                        &ebuf[buf][half][(sg + 1) * 512]);
        }
    };
    // NOTE: stage() above issues 8 gloads/wave covering 16 segs per half across 4 waves.

    stage(0, r8 * 2);                    // tile u(0)=r8, ks=0 flies during prologue

    // enorm -> LDS
    {
        f32x4 v = *reinterpret_cast<const f32x4*>(ws + WS_ENORM_F + tid * 4);
        *reinterpret_cast<f32x4*>(&en_s[tid * 4]) = v;
    }

    // x rows -> split-f16 B-frags: lane l holds x[R+rpair*32+xr][ku*16 + kg*8 .. +8]
    f16x8 Xh[16], Xl[16];
    float xn;
    {
        float s = 0.f;
#pragma unroll
        for (int ku = 0; ku < 16; ++ku) {
            const float* p = x + (size_t)(R + rpair * 32 + xr) * D + ku * 16 + kg * 8;
            f32x4 a = *reinterpret_cast<const f32x4*>(p);
            f32x4 c = *reinterpret_cast<const f32x4*>(p + 4);
            f16 h0=(f16)a.x,h1=(f16)a.y,h2=(f16)a.z,h3=(f16)a.w;
            f16 h4=(f16)c.x,h5=(f16)c.y,h6=(f16)c.z,h7=(f16)c.w;
            Xh[ku] = (f16x8){h0,h1,h2,h3,h4,h5,h6,h7};
            Xl[ku] = (f16x8){(f16)(a.x-(float)h0),(f16)(a.y-(float)h1),
                             (f16)(a.z-(float)h2),(f16)(a.w-(float)h3),
                             (f16)(c.x-(float)h4),(f16)(c.y-(float)h5),
                             (f16)(c.z-(float)h6),(f16)(c.w-(float)h7)};
            s = fmaf(a.x,a.x,fmaf(a.y,a.y,fmaf(a.z,a.z,fmaf(a.w,a.w,
                fmaf(c.x,c.x,fmaf(c.y,c.y,fmaf(c.z,c.z,fmaf(c.w,c.w,s))))))));
        }
        s += __shfl_xor(s, 32, 64);      // partner lane covers the other k-half
        xn = s;
    }
    __syncthreads();                     // unit staged (vmcnt drained), en_s ready

    float bV = 3.4e38f;
    int   bI = 0;
    const ushort* eb0 = &ebuf[0][mhalf][0];
    const ushort* eb1 = &ebuf[1][mhalf][0];

    for (int t = 0; t < 16; ++t) {       // 16 emb-tiles of 32 embs (per M-half)
        const int ut = (t + r8) & 15;    // rotated tile order
        f32x16 accA = {0.f}, accB = {0.f}, accC = {0.f};

        // ---- ks = 0 (buf 0), stage (tile ut, ks1) -> buf 1 ----
        stage(1, ut * 2 + 1);
#pragma unroll
        for (int kstep = 0; kstep < 8; ++kstep) {
            f16x8 Ah = *reinterpret_cast<const f16x8*>(eb0 + kstep * 512 + l * 8);
            f16x8 Al = *reinterpret_cast<const f16x8*>(eb0 + (8 + kstep) * 512 + l * 8);
            accA = __builtin_amdgcn_mfma_f32_32x32x16_f16(Ah, Xh[kstep], accA, 0, 0, 0);
            accB = __builtin_amdgcn_mfma_f32_32x32x16_f16(Al, Xh[kstep], accB, 0, 0, 0);
            accC = __builtin_amdgcn_mfma_f32_32x32x16_f16(Ah, Xl[kstep], accC, 0, 0, 0);
        }
        __syncthreads();                 // eb0 reads done + (ut,ks1) landed

        // ---- ks = 1 (buf 1), stage (tile u(t+1), ks0) -> buf 0 ----
        if (t < 15) stage(0, (((t + 1 + r8) & 15)) * 2);
#pragma unroll
        for (int kstep = 0; kstep < 8; ++kstep) {
            f16x8 Ah = *reinterpret_cast<const f16x8*>(eb1 + kstep * 512 + l * 8);
            f16x8 Al = *reinterpret_cast<const f16x8*>(eb1 + (8 + kstep) * 512 + l * 8);
            accA = __builtin_amdgcn_mfma_f32_32x32x16_f16(Ah, Xh[8 + kstep], accA, 0, 0, 0);
            accB = __builtin_amdgcn_mfma_f32_32x32x16_f16(Al, Xh[8 + kstep], accB, 0, 0, 0);
            accC = __builtin_amdgcn_mfma_f32_32x32x16_f16(Ah, Xl[8 + kstep], accC, 0, 0, 0);
        }
        __syncthreads();                 // eb1 reads done + next (ks0) landed

        // ---- fold: C/D col=lane&31 (x-row), row=(reg&3)+8*(reg>>2)+4*kg
        // rotated order -> explicit idx tie-break keeps np.argmin (lowest index)
        const int mbase = mhalf * 512 + ut * 32;
#pragma unroll
        for (int rq = 0; rq < 4; ++rq) {
            f32x4 en4 = *reinterpret_cast<const f32x4*>(&en_s[mbase + rq * 8 + kg * 4]);
#pragma unroll
            for (int j = 0; j < 4; ++j) {
                int reg = rq * 4 + j;
                int mi  = mbase + rq * 8 + kg * 4 + j;
                float dv = fmaf(-2.f, accA[reg] + accB[reg] + accC[reg], en4[j]);
                if (dv < bV || (dv == bV && mi < bI)) { bV = dv; bI = mi; }
            }
        }
    }

    // reduce lane <-> lane^32 (same x-row, disjoint emb sets), tie -> lower idx
    {
        float ov = __shfl_xor(bV, 32, 64);
        int   oi = __shfl_xor(bI, 32, 64);
        if (ov < bV || (ov == bV && oi < bI)) { bV = ov; bI = oi; }
    }
    if (l < 32) {                        // publish per-wave candidates
        wval[w][xr] = bV;
        widx[w][xr] = bI;
        if (mhalf == 0) xns[rpair * 32 + xr] = xn;
    }
    __syncthreads();

    // pair merge: half-A idx (<512) < half-B idx -> strict < keeps lowest-index tie
    if (tid < 64) {
        int r = tid, g2 = r >> 5, rr = r & 31;
        float v0 = wval[g2 * 2 + 0][rr]; int i0 = widx[g2 * 2 + 0][rr];
        float v1 = wval[g2 * 2 + 1][rr]; int i1 = widx[g2 * 2 + 1][rr];
        float fv; int fi;
        if (v1 < v0) { fv = v1; fi = i1; } else { fv = v0; fi = i0; }
        fidx[r] = fi;
        outIdx[R + r] = (float)fi;
        atomicAdd(ws + 1 + fi, 1.0f);
        float ls = fv + xns[r];
#pragma unroll
        for (int o = 32; o > 0; o >>= 1) ls += __shfl_down(ls, o, 64);
        if (r == 0) atomicAdd(ws, ls);
    }
    __syncthreads();

    // fused gather: quantized = embedding[idx] (exact fp32), nontemporal store
#pragma unroll
    for (int it = 0; it < 16; ++it) {
        int u = it * 256 + tid;
        int row = u >> 6, c4 = u & 63;   // 64 rows x 64 f32x4 units
        f32x4 v = *reinterpret_cast<const f32x4*>(e + (size_t)fidx[row] * D + c4 * 4);
        __builtin_nontemporal_store(v, reinterpret_cast<f32x4*>(outQ + (size_t)(R + row) * D + c4 * 4));
    }
}

// ---------------- fallback fp32 path (only if ws too small) ----------------
__global__ void enorm_kernel(const float* __restrict__ e, float* __restrict__ enorm) {
    int m = blockIdx.x, l = threadIdx.x;
    const f32x4 v = *reinterpret_cast<const f32x4*>(e + m * D + l * 4);
    float s = fmaf(v.x, v.x, fmaf(v.y, v.y, fmaf(v.z, v.z, v.w * v.w)));
#pragma unroll
    for (int o = 32; o > 0; o >>= 1) s += __shfl_down(s, o, 64);
    if (l == 0) enorm[m] = s;
}

__global__ __launch_bounds__(256, 2) void vq_main_kernel(
    const float* __restrict__ x, const float* __restrict__ e,
    float* __restrict__ outQ, float* __restrict__ outIdx, float* __restrict__ ws) {
    __shared__ f32x4 xs[64][64];
    __shared__ float cval[4][64];
    __shared__ int   cidx[4][64];
    __shared__ int   fidx[64];
    const int tid = threadIdx.x, row0 = blockIdx.x * 64;
#pragma unroll
    for (int it = 0; it < 16; ++it) {
        int f = it * 256 + tid, rr = f >> 6, c4 = f & 63;
        xs[rr][c4 ^ (rr & 7)] = *reinterpret_cast<const f32x4*>(x + (row0 + rr) * D + c4 * 4);
    }
    __syncthreads();
    const int r = tid & 63, c = __builtin_amdgcn_readfirstlane(tid >> 6), sw = r & 7;
    float xnorm = 0.f;
    if (c == 0) {
        f32x4 a = (f32x4){0.f,0.f,0.f,0.f};
        for (int d4 = 0; d4 < 64; ++d4) {
            f32x4 xv = xs[r][d4 ^ sw];
            a.x = fmaf(xv.x, xv.x, a.x); a.y = fmaf(xv.y, xv.y, a.y);
            a.z = fmaf(xv.z, xv.z, a.z); a.w = fmaf(xv.w, xv.w, a.w);
        }
        xnorm = (a.x + a.y) + (a.z + a.w);
    }
    const float* __restrict__ enorm = ws + WS_ENORM_F;
    float bestVal = 3.4e38f; int bestIdx = 0;
    for (int chunk = 0; chunk < M / 32; ++chunk) {
        const int m0 = chunk * 32 + c * 8;
        f32x4 acc[8];
#pragma unroll
        for (int mi = 0; mi < 8; ++mi) acc[mi] = (f32x4){0.f,0.f,0.f,0.f};
#pragma unroll 2
        for (int d4 = 0; d4 < 64; ++d4) {
            const f32x4 xv = xs[r][d4 ^ sw];
#pragma unroll
            for (int mi = 0; mi < 8; ++mi) {
                const f32x4 ev = *reinterpret_cast<const f32x4*>(e + (m0 + mi) * D + d4 * 4);
                acc[mi].x = fmaf(xv.x, ev.x, acc[mi].x); acc[mi].y = fmaf(xv.y, ev.y, acc[mi].y);
                acc[mi].z = fmaf(xv.z, ev.z, acc[mi].z); acc[mi].w = fmaf(xv.w, ev.w, acc[mi].w);
            }
        }
#pragma unroll
        for (int mi = 0; mi < 8; ++mi) {
            float dot = (acc[mi].x + acc[mi].y) + (acc[mi].z + acc[mi].w);
            float val = enorm[m0 + mi] - 2.0f * dot;
            if (val < bestVal) { bestVal = val; bestIdx = m0 + mi; }
        }
    }
    cval[c][r] = bestVal; cidx[c][r] = bestIdx;
    __syncthreads();
    if (c == 0) {
        float bv = bestVal; int bi = bestIdx;
#pragma unroll
        for (int cc = 1; cc < 4; ++cc) {
            float v = cval[cc][r]; int i = cidx[cc][r];
            if (v < bv || (v == bv && i < bi)) { bv = v; bi = i; }
        }
        fidx[r] = bi; outIdx[row0 + r] = (float)bi;
        atomicAdd(ws + 1 + bi, 1.0f);
        float dist = bv + xnorm;
#pragma unroll
        for (int o = 32; o > 0; o >>= 1) dist += __shfl_down(dist, o, 64);
        if (r == 0) atomicAdd(ws, dist);
    }
    __syncthreads();
#pragma unroll
    for (int it = 0; it < 16; ++it) {
        int f = it * 256 + tid, rr = f >> 6, c4 = f & 63;
        *reinterpret_cast<f32x4*>(outQ + (row0 + rr) * D + c4 * 4) =
            *reinterpret_cast<const f32x4*>(e + fidx[rr] * D + c4 * 4);
    }
}

// ---------------- finalize: loss + perplexity ----------------
__global__ void vq_final_kernel(const float* __restrict__ ws,
                                float* __restrict__ outLoss, float* __restrict__ outPpl,
                                float invN, float invND) {
    int t = threadIdx.x;
    float p = ws[1 + t] * invN;
    float term = p * logf(p + 1e-10f);
#pragma unroll
    for (int o = 32; o > 0; o >>= 1) term += __shfl_down(term, o, 64);
    __shared__ float s[16];
    if ((t & 63) == 0) s[t >> 6] = term;
    __syncthreads();
    if (t == 0) {
        float tot = 0.f;
#pragma unroll
        for (int i = 0; i < 16; ++i) tot += s[i];
        *outPpl  = expf(-tot);
        *outLoss = 1.25f * ws[0] * invND;
    }
}

extern "C" void kernel_launch(void* const* d_in, const int* in_sizes, int n_in,
                              void* d_out, int out_size, void* d_ws, size_t ws_size,
                              hipStream_t stream) {
    const float* x = (const float*)d_in[0];
    const float* e = (const float*)d_in[1];
    const int NX = in_sizes[0];     // N*D = 8388608
    const int N  = NX / D;          // 32768

    float* out     = (float*)d_out;
    float* outQ    = out;
    float* outLoss = out + NX;
    float* outIdx  = out + NX + 1;
    float* outPpl  = out + NX + 1 + N;
    float* ws      = (float*)d_ws;

    if (ws_size >= WS_NEEDED && (N % ROWS) == 0) {
        prep_kernel<<<513, 256, 0, stream>>>(e, ws);   // block 512 zeroes loss+counts
        vq_fused_kernel<<<N / ROWS, 256, 0, stream>>>(x, e, outQ, outIdx, ws);
    } else {
        (void)hipMemsetAsync(d_ws, 0, 4112, stream);
        enorm_kernel<<<M, 64, 0, stream>>>(e, ws + WS_ENORM_F);
        vq_main_kernel<<<N / 64, 256, 0, stream>>>(x, e, outQ, outIdx, ws);
    }
    vq_final_kernel<<<1, 1024, 0, stream>>>(ws, outLoss, outPpl,
                                            1.0f / (float)N, 1.0f / (float)NX);
}

// Round 19
// 83.334 us; speedup vs baseline: 1.0869x; 1.0533x over previous
//
#include <hip/hip_runtime.h>

// VQEmbedding: x [N=32768, D=256] fp32, embedding [M=1024, D=256] fp32.
// Outputs (flat fp32): quantized [N*D], loss [1], indices [N] (as float), perplexity [1].
// R19: R16 base, ONE change: per ks-phase, ALL 16 A-fragments are loaded into
// registers (Ah[8]/Al[8], batch-issued ds_reads) BEFORE the 24-MFMA cluster --
// removes the per-triple ~120cyc LDS latency edge that 2 waves/SIMD can't hide.
// dist = ||e||^2 - 2 x.e ; loss = 1.25*(sum bestdist + ||x||_F^2)/(N*D).

constexpr int D = 256;
constexpr int M = 1024;
constexpr int ROWS = 64;    // x rows per block (32 per wave, pair-shared)

typedef _Float16 f16;
typedef __attribute__((ext_vector_type(8)))  _Float16 f16x8;
typedef __attribute__((ext_vector_type(4)))  float f32x4;
typedef __attribute__((ext_vector_type(16))) float f32x16;

// ws layout (bytes):
//   [0..4)        loss accumulator (float)
//   [4..4100)     counts (1024 floats, float-idx 1..1025)
//   [4112..8208)  enorm (1024 floats, float-idx 1028..2052)
//   [8320..1056896)  e split-f16 table, A-frag order for mfma_32x32x16_f16:
//     16B elem v: lane=v&63, u=(v>>6)&15, ksl=(v>>10)&1, t32=v>>11;
//     kstep=u&7, spl=u>>3 (0=hi,1=lo);
//     content = split(e[t32*32+(lane&31)][(ksl*8+kstep)*16+(lane>>5)*8 .. +8]).
constexpr size_t WS_ENORM_F = 1028;
constexpr size_t WS_TAB_B   = 8320;
constexpr size_t WS_NEEDED  = 1056896;

__device__ inline void gload_lds16(const void* g, void* l) {
    __builtin_amdgcn_global_load_lds(
        (const __attribute__((address_space(1))) unsigned int*)(g),
        (__attribute__((address_space(3))) unsigned int*)(l), 16, 0, 0);
}

// ---------------- prep: A-frag-ordered split-f16 e table + ||e||^2 + ws zero ----------------
__global__ __launch_bounds__(256) void prep_kernel(const float* __restrict__ e,
                                                   float* __restrict__ ws) {
    const int b = blockIdx.x, t = threadIdx.x;
    if (b < 256) {
        int v    = b * 256 + t;               // 16B element index
        int lane = v & 63, u = (v >> 6) & 15;
        int ksl  = (v >> 10) & 1, t32 = v >> 11;
        int kstep = u & 7, spl = u >> 3;
        int row  = t32 * 32 + (lane & 31);
        int col0 = (ksl * 8 + kstep) * 16 + (lane >> 5) * 8;
        const float* p = e + (size_t)row * D + col0;
        f32x4 a = *reinterpret_cast<const f32x4*>(p);
        f32x4 c = *reinterpret_cast<const f32x4*>(p + 4);
        f16 h0=(f16)a.x,h1=(f16)a.y,h2=(f16)a.z,h3=(f16)a.w;
        f16 h4=(f16)c.x,h5=(f16)c.y,h6=(f16)c.z,h7=(f16)c.w;
        f16x8 out;
        if (spl == 0) out = (f16x8){h0,h1,h2,h3,h4,h5,h6,h7};
        else          out = (f16x8){(f16)(a.x-(float)h0),(f16)(a.y-(float)h1),
                                    (f16)(a.z-(float)h2),(f16)(a.w-(float)h3),
                                    (f16)(c.x-(float)h4),(f16)(c.y-(float)h5),
                                    (f16)(c.z-(float)h6),(f16)(c.w-(float)h7)};
        *reinterpret_cast<f16x8*>((char*)ws + WS_TAB_B + (size_t)v * 16) = out;
    } else if (b < 512) {
        int row  = (b - 256) * 4 + (t >> 6);  // 1024 rows over blocks 256..511
        int lane = t & 63;
        f32x4 a = *reinterpret_cast<const f32x4*>(e + (size_t)row * D + lane * 4);
        float s = fmaf(a.x, a.x, fmaf(a.y, a.y, fmaf(a.z, a.z, a.w * a.w)));
#pragma unroll
        for (int o = 32; o > 0; o >>= 1) s += __shfl_down(s, o, 64);
        if (lane == 0) ws[WS_ENORM_F + row] = s;
    } else {
        for (int i = t; i < 1026; i += 256) ws[i] = 0.f;   // loss + counts
    }
}

// ---------------- fused main kernel: M-split waves, 32x32x16, reg-batched A ----------------
__global__ __launch_bounds__(256, 2) void vq_fused_kernel(
    const float* __restrict__ x, const float* __restrict__ e,
    float* __restrict__ outQ, float* __restrict__ outIdx, float* __restrict__ ws)
{
    __shared__ ushort ebuf[2][2][8192]; // [buf][mhalf][16KB A-frag region]
    __shared__ float  en_s[M];          // 4 KB
    __shared__ float  wval[4][32];
    __shared__ int    widx[4][32];
    __shared__ float  xns[ROWS];
    __shared__ int    fidx[ROWS];

    const int tid   = threadIdx.x;
    const int w     = __builtin_amdgcn_readfirstlane(tid >> 6);  // wave 0..3
    const int l     = tid & 63;
    const int rpair = w >> 1;            // row group: rows R + rpair*32 + (l&31)
    const int mhalf = w & 1;             // codebook half: embs [mhalf*512, +512)
    const int R     = blockIdx.x * ROWS;
    const int xr    = l & 31;            // this lane's x-row (B col)
    const int kg    = l >> 5;            // k-group (0/1) within 16-wide k blocks
    const char* tab = (const char*)ws + WS_TAB_B;

    auto stage = [&](int buf, int g) {
        int tt = g >> 1, ks = g & 1;
#pragma unroll
        for (int i = 0; i < 8; ++i) {
            int S = w * 8 + i, half = S >> 4, sg = S & 15;
            gload_lds16(tab + (size_t)(((half * 16 + tt) * 2 + ks)) * 16384 + sg * 1024 + l * 16,
                        &ebuf[buf][half][sg * 512]);
        }
    };
    stage(0, 0);                         // unit 0 flies during the prologue

    // enorm -> LDS
    {
        f32x4 v = *reinterpret_cast<const f32x4*>(ws + WS_ENORM_F + tid * 4);
        *reinterpret_cast<f32x4*>(&en_s[tid * 4]) = v;
    }

    // x rows -> split-f16 B-frags: lane l holds x[R+rpair*32+xr][ku*16 + kg*8 .. +8]
    f16x8 Xh[16], Xl[16];
    float xn;
    {
        float s = 0.f;
#pragma unroll
        for (int ku = 0; ku < 16; ++ku) {
            const float* p = x + (size_t)(R + rpair * 32 + xr) * D + ku * 16 + kg * 8;
            f32x4 a = *reinterpret_cast<const f32x4*>(p);
            f32x4 c = *reinterpret_cast<const f32x4*>(p + 4);
            f16 h0=(f16)a.x,h1=(f16)a.y,h2=(f16)a.z,h3=(f16)a.w;
            f16 h4=(f16)c.x,h5=(f16)c.y,h6=(f16)c.z,h7=(f16)c.w;
            Xh[ku] = (f16x8){h0,h1,h2,h3,h4,h5,h6,h7};
            Xl[ku] = (f16x8){(f16)(a.x-(float)h0),(f16)(a.y-(float)h1),
                             (f16)(a.z-(float)h2),(f16)(a.w-(float)h3),
                             (f16)(c.x-(float)h4),(f16)(c.y-(float)h5),
                             (f16)(c.z-(float)h6),(f16)(c.w-(float)h7)};
            s = fmaf(a.x,a.x,fmaf(a.y,a.y,fmaf(a.z,a.z,fmaf(a.w,a.w,
                fmaf(c.x,c.x,fmaf(c.y,c.y,fmaf(c.z,c.z,fmaf(c.w,c.w,s))))))));
        }
        s += __shfl_xor(s, 32, 64);      // partner lane covers the other k-half
        xn = s;
    }
    __syncthreads();                     // unit 0 staged (vmcnt drained), en_s ready

    float bV = 3.4e38f;
    int   bI = 0;
    const ushort* eb0 = &ebuf[0][mhalf][0];
    const ushort* eb1 = &ebuf[1][mhalf][0];

    for (int t = 0; t < 16; ++t) {       // 16 emb-tiles of 32 embs (per M-half)
        f32x16 accA = {0.f}, accB = {0.f}, accC = {0.f};   // 3 indep 8-deep chains
        f16x8 Ah[8], Al[8];

        // ---- ks = 0 (buf 0), stage unit 2t+1 -> buf 1 ----
        stage(1, 2 * t + 1);
#pragma unroll
        for (int kstep = 0; kstep < 8; ++kstep) {          // batch-issue all 16 ds_reads
            Ah[kstep] = *reinterpret_cast<const f16x8*>(eb0 + kstep * 512 + l * 8);
            Al[kstep] = *reinterpret_cast<const f16x8*>(eb0 + (8 + kstep) * 512 + l * 8);
        }
        __builtin_amdgcn_s_setprio(1);
#pragma unroll
        for (int kstep = 0; kstep < 8; ++kstep) {          // pure-reg MFMA cluster
            accA = __builtin_amdgcn_mfma_f32_32x32x16_f16(Ah[kstep], Xh[kstep], accA, 0, 0, 0);
            accB = __builtin_amdgcn_mfma_f32_32x32x16_f16(Al[kstep], Xh[kstep], accB, 0, 0, 0);
            accC = __builtin_amdgcn_mfma_f32_32x32x16_f16(Ah[kstep], Xl[kstep], accC, 0, 0, 0);
        }
        __builtin_amdgcn_s_setprio(0);
        __syncthreads();                 // eb0 reads done + unit 2t+1 landed

        // ---- ks = 1 (buf 1), stage unit 2t+2 -> buf 0 ----
        if (t < 15) stage(0, 2 * t + 2);
#pragma unroll
        for (int kstep = 0; kstep < 8; ++kstep) {          // batch-issue all 16 ds_reads
            Ah[kstep] = *reinterpret_cast<const f16x8*>(eb1 + kstep * 512 + l * 8);
            Al[kstep] = *reinterpret_cast<const f16x8*>(eb1 + (8 + kstep) * 512 + l * 8);
        }
        __builtin_amdgcn_s_setprio(1);
#pragma unroll
        for (int kstep = 0; kstep < 8; ++kstep) {          // pure-reg MFMA cluster
            accA = __builtin_amdgcn_mfma_f32_32x32x16_f16(Ah[kstep], Xh[8 + kstep], accA, 0, 0, 0);
            accB = __builtin_amdgcn_mfma_f32_32x32x16_f16(Al[kstep], Xh[8 + kstep], accB, 0, 0, 0);
            accC = __builtin_amdgcn_mfma_f32_32x32x16_f16(Ah[kstep], Xl[8 + kstep], accC, 0, 0, 0);
        }
        __builtin_amdgcn_s_setprio(0);
        __syncthreads();                 // eb1 reads done + unit 2t+2 landed

        // ---- fold: C/D col=lane&31 (x-row), row=(reg&3)+8*(reg>>2)+4*kg
        const int mbase = mhalf * 512 + t * 32;
#pragma unroll
        for (int rq = 0; rq < 4; ++rq) {
            f32x4 en4 = *reinterpret_cast<const f32x4*>(&en_s[mbase + rq * 8 + kg * 4]);
#pragma unroll
            for (int j = 0; j < 4; ++j) {
                int reg = rq * 4 + j;
                int mi  = mbase + rq * 8 + kg * 4 + j;
                float dv = fmaf(-2.f, accA[reg] + accB[reg] + accC[reg], en4[j]);
                if (dv < bV) { bV = dv; bI = mi; }
            }
        }
    }

    // reduce lane <-> lane^32 (same x-row, disjoint emb sets), tie -> lower idx
    {
        float ov = __shfl_xor(bV, 32, 64);
        int   oi = __shfl_xor(bI, 32, 64);
        if (ov < bV || (ov == bV && oi < bI)) { bV = ov; bI = oi; }
    }
    if (l < 32) {                        // publish per-wave candidates
        wval[w][xr] = bV;
        widx[w][xr] = bI;
        if (mhalf == 0) xns[rpair * 32 + xr] = xn;
    }
    __syncthreads();

    // pair merge: half-A idx (<512) < half-B idx -> strict < keeps lowest-index tie
    if (tid < 64) {
        int r = tid, g2 = r >> 5, rr = r & 31;
        float v0 = wval[g2 * 2 + 0][rr]; int i0 = widx[g2 * 2 + 0][rr];
        float v1 = wval[g2 * 2 + 1][rr]; int i1 = widx[g2 * 2 + 1][rr];
        float fv; int fi;
        if (v1 < v0) { fv = v1; fi = i1; } else { fv = v0; fi = i0; }
        fidx[r] = fi;
        outIdx[R + r] = (float)fi;
        atomicAdd(ws + 1 + fi, 1.0f);
        float ls = fv + xns[r];
#pragma unroll
        for (int o = 32; o > 0; o >>= 1) ls += __shfl_down(ls, o, 64);
        if (r == 0) atomicAdd(ws, ls);
    }
    __syncthreads();

    // fused gather: quantized = embedding[idx] (exact fp32), nontemporal store
#pragma unroll
    for (int it = 0; it < 16; ++it) {
        int u = it * 256 + tid;
        int row = u >> 6, c4 = u & 63;   // 64 rows x 64 f32x4 units
        f32x4 v = *reinterpret_cast<const f32x4*>(e + (size_t)fidx[row] * D + c4 * 4);
        __builtin_nontemporal_store(v, reinterpret_cast<f32x4*>(outQ + (size_t)(R + row) * D + c4 * 4));
    }
}

// ---------------- fallback fp32 path (only if ws too small) ----------------
__global__ void enorm_kernel(const float* __restrict__ e, float* __restrict__ enorm) {
    int m = blockIdx.x, l = threadIdx.x;
    const f32x4 v = *reinterpret_cast<const f32x4*>(e + m * D + l * 4);
    float s = fmaf(v.x, v.x, fmaf(v.y, v.y, fmaf(v.z, v.z, v.w * v.w)));
#pragma unroll
    for (int o = 32; o > 0; o >>= 1) s += __shfl_down(s, o, 64);
    if (l == 0) enorm[m] = s;
}

__global__ __launch_bounds__(256, 2) void vq_main_kernel(
    const float* __restrict__ x, const float* __restrict__ e,
    float* __restrict__ outQ, float* __restrict__ outIdx, float* __restrict__ ws) {
    __shared__ f32x4 xs[64][64];
    __shared__ float cval[4][64];
    __shared__ int   cidx[4][64];
    __shared__ int   fidx[64];
    const int tid = threadIdx.x, row0 = blockIdx.x * 64;
#pragma unroll
    for (int it = 0; it < 16; ++it) {
        int f = it * 256 + tid, rr = f >> 6, c4 = f & 63;
        xs[rr][c4 ^ (rr & 7)] = *reinterpret_cast<const f32x4*>(x + (row0 + rr) * D + c4 * 4);
    }
    __syncthreads();
    const int r = tid & 63, c = __builtin_amdgcn_readfirstlane(tid >> 6), sw = r & 7;
    float xnorm = 0.f;
    if (c == 0) {
        f32x4 a = (f32x4){0.f,0.f,0.f,0.f};
        for (int d4 = 0; d4 < 64; ++d4) {
            f32x4 xv = xs[r][d4 ^ sw];
            a.x = fmaf(xv.x, xv.x, a.x); a.y = fmaf(xv.y, xv.y, a.y);
            a.z = fmaf(xv.z, xv.z, a.z); a.w = fmaf(xv.w, xv.w, a.w);
        }
        xnorm = (a.x + a.y) + (a.z + a.w);
    }
    const float* __restrict__ enorm = ws + WS_ENORM_F;
    float bestVal = 3.4e38f; int bestIdx = 0;
    for (int chunk = 0; chunk < M / 32; ++chunk) {
        const int m0 = chunk * 32 + c * 8;
        f32x4 acc[8];
#pragma unroll
        for (int mi = 0; mi < 8; ++mi) acc[mi] = (f32x4){0.f,0.f,0.f,0.f};
#pragma unroll 2
        for (int d4 = 0; d4 < 64; ++d4) {
            const f32x4 xv = xs[r][d4 ^ sw];
#pragma unroll
            for (int mi = 0; mi < 8; ++mi) {
                const f32x4 ev = *reinterpret_cast<const f32x4*>(e + (m0 + mi) * D + d4 * 4);
                acc[mi].x = fmaf(xv.x, ev.x, acc[mi].x); acc[mi].y = fmaf(xv.y, ev.y, acc[mi].y);
                acc[mi].z = fmaf(xv.z, ev.z, acc[mi].z); acc[mi].w = fmaf(xv.w, ev.w, acc[mi].w);
            }
        }
#pragma unroll
        for (int mi = 0; mi < 8; ++mi) {
            float dot = (acc[mi].x + acc[mi].y) + (acc[mi].z + acc[mi].w);
            float val = enorm[m0 + mi] - 2.0f * dot;
            if (val < bestVal) { bestVal = val; bestIdx = m0 + mi; }
        }
    }
    cval[c][r] = bestVal; cidx[c][r] = bestIdx;
    __syncthreads();
    if (c == 0) {
        float bv = bestVal; int bi = bestIdx;
#pragma unroll
        for (int cc = 1; cc < 4; ++cc) {
            float v = cval[cc][r]; int i = cidx[cc][r];
            if (v < bv || (v == bv && i < bi)) { bv = v; bi = i; }
        }
        fidx[r] = bi; outIdx[row0 + r] = (float)bi;
        atomicAdd(ws + 1 + bi, 1.0f);
        float dist = bv + xnorm;
#pragma unroll
        for (int o = 32; o > 0; o >>= 1) dist += __shfl_down(dist, o, 64);
        if (r == 0) atomicAdd(ws, dist);
    }
    __syncthreads();
#pragma unroll
    for (int it = 0; it < 16; ++it) {
        int f = it * 256 + tid, rr = f >> 6, c4 = f & 63;
        *reinterpret_cast<f32x4*>(outQ + (row0 + rr) * D + c4 * 4) =
            *reinterpret_cast<const f32x4*>(e + fidx[rr] * D + c4 * 4);
    }
}

// ---------------- finalize: loss + perplexity ----------------
__global__ void vq_final_kernel(const float* __restrict__ ws,
                                float* __restrict__ outLoss, float* __restrict__ outPpl,
                                float invN, float invND) {
    int t = threadIdx.x;
    float p = ws[1 + t] * invN;
    float term = p * logf(p + 1e-10f);
#pragma unroll
    for (int o = 32; o > 0; o >>= 1) term += __shfl_down(term, o, 64);
    __shared__ float s[16];
    if ((t & 63) == 0) s[t >> 6] = term;
    __syncthreads();
    if (t == 0) {
        float tot = 0.f;
#pragma unroll
        for (int i = 0; i < 16; ++i) tot += s[i];
        *outPpl  = expf(-tot);
        *outLoss = 1.25f * ws[0] * invND;
    }
}

extern "C" void kernel_launch(void* const* d_in, const int* in_sizes, int n_in,
                              void* d_out, int out_size, void* d_ws, size_t ws_size,
                              hipStream_t stream) {
    const float* x = (const float*)d_in[0];
    const float* e = (const float*)d_in[1];
    const int NX = in_sizes[0];     // N*D = 8388608
    const int N  = NX / D;          // 32768

    float* out     = (float*)d_out;
    float* outQ    = out;
    float* outLoss = out + NX;
    float* outIdx  = out + NX + 1;
    float* outPpl  = out + NX + 1 + N;
    float* ws      = (float*)d_ws;

    if (ws_size >= WS_NEEDED && (N % ROWS) == 0) {
        prep_kernel<<<513, 256, 0, stream>>>(e, ws);   // block 512 zeroes loss+counts
        vq_fused_kernel<<<N / ROWS, 256, 0, stream>>>(x, e, outQ, outIdx, ws);
    } else {
        (void)hipMemsetAsync(d_ws, 0, 4112, stream);
        enorm_kernel<<<M, 64, 0, stream>>>(e, ws + WS_ENORM_F);
        vq_main_kernel<<<N / 64, 256, 0, stream>>>(x, e, outQ, outIdx, ws);
    }
    vq_final_kernel<<<1, 1024, 0, stream>>>(ws, outLoss, outPpl,
                                            1.0f / (float)N, 1.0f / (float)NX);
}

// Round 20
// 79.656 us; speedup vs baseline: 1.1371x; 1.0462x over previous
//
#include <hip/hip_runtime.h>

// VQEmbedding: x [N=32768, D=256] fp32, embedding [M=1024, D=256] fp32.
// Outputs (flat fp32): quantized [N*D], loss [1], indices [N] (as float), perplexity [1].
// R20 = R16 champion restore (best measured: 79.9us total, fused 72.5us).
// 64 rows/block, 4 waves M-split (wave = 32 x-rows x 512 embs), 32x32x16 MFMA,
// 3 independent 8-deep chains, double-buffered 16KB e-units via global_load_lds,
// plain __syncthreads skeleton, 2 blocks/CU. Separate prep/final kernels.
// dist = ||e||^2 - 2 x.e ; loss = 1.25*(sum bestdist + ||x||_F^2)/(N*D).
//
// Structural ceiling note: split-f16 X-residency (128 VGPR) caps occupancy at
// 2 waves/SIMD; at that occupancy the per-phase MFMA(1550cyc/SIMD) + LDS(1536/CU)
// + stage(1170/CU) bills serialize behind the phase barrier. 12 controlled
// experiments (R8-R19) on sync/geometry/chains all regressed or were neutral.

constexpr int D = 256;
constexpr int M = 1024;
constexpr int ROWS = 64;    // x rows per block (32 per wave, pair-shared)

typedef _Float16 f16;
typedef __attribute__((ext_vector_type(8)))  _Float16 f16x8;
typedef __attribute__((ext_vector_type(4)))  float f32x4;
typedef __attribute__((ext_vector_type(16))) float f32x16;

// ws layout (bytes):
//   [0..4)        loss accumulator (float)
//   [4..4100)     counts (1024 floats, float-idx 1..1025)
//   [4112..8208)  enorm (1024 floats, float-idx 1028..2052)
//   [8320..1056896)  e split-f16 table, A-frag order for mfma_32x32x16_f16:
//     16B elem v: lane=v&63, u=(v>>6)&15, ksl=(v>>10)&1, t32=v>>11;
//     kstep=u&7, spl=u>>3 (0=hi,1=lo);
//     content = split(e[t32*32+(lane&31)][(ksl*8+kstep)*16+(lane>>5)*8 .. +8]).
constexpr size_t WS_ENORM_F = 1028;
constexpr size_t WS_TAB_B   = 8320;
constexpr size_t WS_NEEDED  = 1056896;

__device__ inline void gload_lds16(const void* g, void* l) {
    __builtin_amdgcn_global_load_lds(
        (const __attribute__((address_space(1))) unsigned int*)(g),
        (__attribute__((address_space(3))) unsigned int*)(l), 16, 0, 0);
}

// ---------------- prep: A-frag-ordered split-f16 e table + ||e||^2 + ws zero ----------------
__global__ __launch_bounds__(256) void prep_kernel(const float* __restrict__ e,
                                                   float* __restrict__ ws) {
    const int b = blockIdx.x, t = threadIdx.x;
    if (b < 256) {
        int v    = b * 256 + t;               // 16B element index
        int lane = v & 63, u = (v >> 6) & 15;
        int ksl  = (v >> 10) & 1, t32 = v >> 11;
        int kstep = u & 7, spl = u >> 3;
        int row  = t32 * 32 + (lane & 31);
        int col0 = (ksl * 8 + kstep) * 16 + (lane >> 5) * 8;
        const float* p = e + (size_t)row * D + col0;
        f32x4 a = *reinterpret_cast<const f32x4*>(p);
        f32x4 c = *reinterpret_cast<const f32x4*>(p + 4);
        f16 h0=(f16)a.x,h1=(f16)a.y,h2=(f16)a.z,h3=(f16)a.w;
        f16 h4=(f16)c.x,h5=(f16)c.y,h6=(f16)c.z,h7=(f16)c.w;
        f16x8 out;
        if (spl == 0) out = (f16x8){h0,h1,h2,h3,h4,h5,h6,h7};
        else          out = (f16x8){(f16)(a.x-(float)h0),(f16)(a.y-(float)h1),
                                    (f16)(a.z-(float)h2),(f16)(a.w-(float)h3),
                                    (f16)(c.x-(float)h4),(f16)(c.y-(float)h5),
                                    (f16)(c.z-(float)h6),(f16)(c.w-(float)h7)};
        *reinterpret_cast<f16x8*>((char*)ws + WS_TAB_B + (size_t)v * 16) = out;
    } else if (b < 512) {
        int row  = (b - 256) * 4 + (t >> 6);  // 1024 rows over blocks 256..511
        int lane = t & 63;
        f32x4 a = *reinterpret_cast<const f32x4*>(e + (size_t)row * D + lane * 4);
        float s = fmaf(a.x, a.x, fmaf(a.y, a.y, fmaf(a.z, a.z, a.w * a.w)));
#pragma unroll
        for (int o = 32; o > 0; o >>= 1) s += __shfl_down(s, o, 64);
        if (lane == 0) ws[WS_ENORM_F + row] = s;
    } else {
        for (int i = t; i < 1026; i += 256) ws[i] = 0.f;   // loss + counts
    }
}

// ---------------- fused main kernel: M-split waves, 32x32x16 MFMA, 3 chains ----------------
__global__ __launch_bounds__(256, 2) void vq_fused_kernel(
    const float* __restrict__ x, const float* __restrict__ e,
    float* __restrict__ outQ, float* __restrict__ outIdx, float* __restrict__ ws)
{
    __shared__ ushort ebuf[2][2][8192]; // [buf][mhalf][16KB A-frag region]
    __shared__ float  en_s[M];          // 4 KB
    __shared__ float  wval[4][32];
    __shared__ int    widx[4][32];
    __shared__ float  xns[ROWS];
    __shared__ int    fidx[ROWS];

    const int tid   = threadIdx.x;
    const int w     = __builtin_amdgcn_readfirstlane(tid >> 6);  // wave 0..3
    const int l     = tid & 63;
    const int rpair = w >> 1;            // row group: rows R + rpair*32 + (l&31)
    const int mhalf = w & 1;             // codebook half: embs [mhalf*512, +512)
    const int R     = blockIdx.x * ROWS;
    const int xr    = l & 31;            // this lane's x-row (B col)
    const int kg    = l >> 5;            // k-group (0/1) within 16-wide k blocks
    const char* tab = (const char*)ws + WS_TAB_B;

    auto stage = [&](int buf, int g) {
        int tt = g >> 1, ks = g & 1;
#pragma unroll
        for (int i = 0; i < 8; ++i) {
            int S = w * 8 + i, half = S >> 4, sg = S & 15;
            gload_lds16(tab + (size_t)(((half * 16 + tt) * 2 + ks)) * 16384 + sg * 1024 + l * 16,
                        &ebuf[buf][half][sg * 512]);
        }
    };
    stage(0, 0);                         // unit 0 flies during the prologue

    // enorm -> LDS
    {
        f32x4 v = *reinterpret_cast<const f32x4*>(ws + WS_ENORM_F + tid * 4);
        *reinterpret_cast<f32x4*>(&en_s[tid * 4]) = v;
    }

    // x rows -> split-f16 B-frags: lane l holds x[R+rpair*32+xr][ku*16 + kg*8 .. +8]
    f16x8 Xh[16], Xl[16];
    float xn;
    {
        float s = 0.f;
#pragma unroll
        for (int ku = 0; ku < 16; ++ku) {
            const float* p = x + (size_t)(R + rpair * 32 + xr) * D + ku * 16 + kg * 8;
            f32x4 a = *reinterpret_cast<const f32x4*>(p);
            f32x4 c = *reinterpret_cast<const f32x4*>(p + 4);
            f16 h0=(f16)a.x,h1=(f16)a.y,h2=(f16)a.z,h3=(f16)a.w;
            f16 h4=(f16)c.x,h5=(f16)c.y,h6=(f16)c.z,h7=(f16)c.w;
            Xh[ku] = (f16x8){h0,h1,h2,h3,h4,h5,h6,h7};
            Xl[ku] = (f16x8){(f16)(a.x-(float)h0),(f16)(a.y-(float)h1),
                             (f16)(a.z-(float)h2),(f16)(a.w-(float)h3),
                             (f16)(c.x-(float)h4),(f16)(c.y-(float)h5),
                             (f16)(c.z-(float)h6),(f16)(c.w-(float)h7)};
            s = fmaf(a.x,a.x,fmaf(a.y,a.y,fmaf(a.z,a.z,fmaf(a.w,a.w,
                fmaf(c.x,c.x,fmaf(c.y,c.y,fmaf(c.z,c.z,fmaf(c.w,c.w,s))))))));
        }
        s += __shfl_xor(s, 32, 64);      // partner lane covers the other k-half
        xn = s;
    }
    __syncthreads();                     // unit 0 staged (vmcnt drained), en_s ready

    float bV = 3.4e38f;
    int   bI = 0;
    const ushort* eb0 = &ebuf[0][mhalf][0];
    const ushort* eb1 = &ebuf[1][mhalf][0];

    for (int t = 0; t < 16; ++t) {       // 16 emb-tiles of 32 embs (per M-half)
        f32x16 accA = {0.f}, accB = {0.f}, accC = {0.f};   // 3 indep 8-deep chains

        // ---- ks = 0 (buf 0), stage unit 2t+1 -> buf 1 ----
        stage(1, 2 * t + 1);
        __builtin_amdgcn_s_setprio(1);
#pragma unroll
        for (int kstep = 0; kstep < 8; ++kstep) {
            f16x8 Ah = *reinterpret_cast<const f16x8*>(eb0 + kstep * 512 + l * 8);
            f16x8 Al = *reinterpret_cast<const f16x8*>(eb0 + (8 + kstep) * 512 + l * 8);
            accA = __builtin_amdgcn_mfma_f32_32x32x16_f16(Ah, Xh[kstep], accA, 0, 0, 0);
            accB = __builtin_amdgcn_mfma_f32_32x32x16_f16(Al, Xh[kstep], accB, 0, 0, 0);
            accC = __builtin_amdgcn_mfma_f32_32x32x16_f16(Ah, Xl[kstep], accC, 0, 0, 0);
        }
        __builtin_amdgcn_s_setprio(0);
        __syncthreads();                 // eb0 reads done + unit 2t+1 landed

        // ---- ks = 1 (buf 1), stage unit 2t+2 -> buf 0 ----
        if (t < 15) stage(0, 2 * t + 2);
        __builtin_amdgcn_s_setprio(1);
#pragma unroll
        for (int kstep = 0; kstep < 8; ++kstep) {
            f16x8 Ah = *reinterpret_cast<const f16x8*>(eb1 + kstep * 512 + l * 8);
            f16x8 Al = *reinterpret_cast<const f16x8*>(eb1 + (8 + kstep) * 512 + l * 8);
            accA = __builtin_amdgcn_mfma_f32_32x32x16_f16(Ah, Xh[8 + kstep], accA, 0, 0, 0);
            accB = __builtin_amdgcn_mfma_f32_32x32x16_f16(Al, Xh[8 + kstep], accB, 0, 0, 0);
            accC = __builtin_amdgcn_mfma_f32_32x32x16_f16(Ah, Xl[8 + kstep], accC, 0, 0, 0);
        }
        __builtin_amdgcn_s_setprio(0);
        __syncthreads();                 // eb1 reads done + unit 2t+2 landed

        // ---- fold: C/D col=lane&31 (x-row), row=(reg&3)+8*(reg>>2)+4*kg
        const int mbase = mhalf * 512 + t * 32;
#pragma unroll
        for (int rq = 0; rq < 4; ++rq) {
            f32x4 en4 = *reinterpret_cast<const f32x4*>(&en_s[mbase + rq * 8 + kg * 4]);
#pragma unroll
            for (int j = 0; j < 4; ++j) {
                int reg = rq * 4 + j;
                int mi  = mbase + rq * 8 + kg * 4 + j;
                float dv = fmaf(-2.f, accA[reg] + accB[reg] + accC[reg], en4[j]);
                if (dv < bV) { bV = dv; bI = mi; }
            }
        }
    }

    // reduce lane <-> lane^32 (same x-row, disjoint emb sets), tie -> lower idx
    {
        float ov = __shfl_xor(bV, 32, 64);
        int   oi = __shfl_xor(bI, 32, 64);
        if (ov < bV || (ov == bV && oi < bI)) { bV = ov; bI = oi; }
    }
    if (l < 32) {                        // publish per-wave candidates
        wval[w][xr] = bV;
        widx[w][xr] = bI;
        if (mhalf == 0) xns[rpair * 32 + xr] = xn;
    }
    __syncthreads();

    // pair merge: half-A idx (<512) < half-B idx -> strict < keeps lowest-index tie
    if (tid < 64) {
        int r = tid, g2 = r >> 5, rr = r & 31;
        float v0 = wval[g2 * 2 + 0][rr]; int i0 = widx[g2 * 2 + 0][rr];
        float v1 = wval[g2 * 2 + 1][rr]; int i1 = widx[g2 * 2 + 1][rr];
        float fv; int fi;
        if (v1 < v0) { fv = v1; fi = i1; } else { fv = v0; fi = i0; }
        fidx[r] = fi;
        outIdx[R + r] = (float)fi;
        atomicAdd(ws + 1 + fi, 1.0f);
        float ls = fv + xns[r];
#pragma unroll
        for (int o = 32; o > 0; o >>= 1) ls += __shfl_down(ls, o, 64);
        if (r == 0) atomicAdd(ws, ls);
    }
    __syncthreads();

    // fused gather: quantized = embedding[idx] (exact fp32), nontemporal store
#pragma unroll
    for (int it = 0; it < 16; ++it) {
        int u = it * 256 + tid;
        int row = u >> 6, c4 = u & 63;   // 64 rows x 64 f32x4 units
        f32x4 v = *reinterpret_cast<const f32x4*>(e + (size_t)fidx[row] * D + c4 * 4);
        __builtin_nontemporal_store(v, reinterpret_cast<f32x4*>(outQ + (size_t)(R + row) * D + c4 * 4));
    }
}

// ---------------- fallback fp32 path (only if ws too small) ----------------
__global__ void enorm_kernel(const float* __restrict__ e, float* __restrict__ enorm) {
    int m = blockIdx.x, l = threadIdx.x;
    const f32x4 v = *reinterpret_cast<const f32x4*>(e + m * D + l * 4);
    float s = fmaf(v.x, v.x, fmaf(v.y, v.y, fmaf(v.z, v.z, v.w * v.w)));
#pragma unroll
    for (int o = 32; o > 0; o >>= 1) s += __shfl_down(s, o, 64);
    if (l == 0) enorm[m] = s;
}

__global__ __launch_bounds__(256, 2) void vq_main_kernel(
    const float* __restrict__ x, const float* __restrict__ e,
    float* __restrict__ outQ, float* __restrict__ outIdx, float* __restrict__ ws) {
    __shared__ f32x4 xs[64][64];
    __shared__ float cval[4][64];
    __shared__ int   cidx[4][64];
    __shared__ int   fidx[64];
    const int tid = threadIdx.x, row0 = blockIdx.x * 64;
#pragma unroll
    for (int it = 0; it < 16; ++it) {
        int f = it * 256 + tid, rr = f >> 6, c4 = f & 63;
        xs[rr][c4 ^ (rr & 7)] = *reinterpret_cast<const f32x4*>(x + (row0 + rr) * D + c4 * 4);
    }
    __syncthreads();
    const int r = tid & 63, c = __builtin_amdgcn_readfirstlane(tid >> 6), sw = r & 7;
    float xnorm = 0.f;
    if (c == 0) {
        f32x4 a = (f32x4){0.f,0.f,0.f,0.f};
        for (int d4 = 0; d4 < 64; ++d4) {
            f32x4 xv = xs[r][d4 ^ sw];
            a.x = fmaf(xv.x, xv.x, a.x); a.y = fmaf(xv.y, xv.y, a.y);
            a.z = fmaf(xv.z, xv.z, a.z); a.w = fmaf(xv.w, xv.w, a.w);
        }
        xnorm = (a.x + a.y) + (a.z + a.w);
    }
    const float* __restrict__ enorm = ws + WS_ENORM_F;
    float bestVal = 3.4e38f; int bestIdx = 0;
    for (int chunk = 0; chunk < M / 32; ++chunk) {
        const int m0 = chunk * 32 + c * 8;
        f32x4 acc[8];
#pragma unroll
        for (int mi = 0; mi < 8; ++mi) acc[mi] = (f32x4){0.f,0.f,0.f,0.f};
#pragma unroll 2
        for (int d4 = 0; d4 < 64; ++d4) {
            const f32x4 xv = xs[r][d4 ^ sw];
#pragma unroll
            for (int mi = 0; mi < 8; ++mi) {
                const f32x4 ev = *reinterpret_cast<const f32x4*>(e + (m0 + mi) * D + d4 * 4);
                acc[mi].x = fmaf(xv.x, ev.x, acc[mi].x); acc[mi].y = fmaf(xv.y, ev.y, acc[mi].y);
                acc[mi].z = fmaf(xv.z, ev.z, acc[mi].z); acc[mi].w = fmaf(xv.w, ev.w, acc[mi].w);
            }
        }
#pragma unroll
        for (int mi = 0; mi < 8; ++mi) {
            float dot = (acc[mi].x + acc[mi].y) + (acc[mi].z + acc[mi].w);
            float val = enorm[m0 + mi] - 2.0f * dot;
            if (val < bestVal) { bestVal = val; bestIdx = m0 + mi; }
        }
    }
    cval[c][r] = bestVal; cidx[c][r] = bestIdx;
    __syncthreads();
    if (c == 0) {
        float bv = bestVal; int bi = bestIdx;
#pragma unroll
        for (int cc = 1; cc < 4; ++cc) {
            float v = cval[cc][r]; int i = cidx[cc][r];
            if (v < bv || (v == bv && i < bi)) { bv = v; bi = i; }
        }
        fidx[r] = bi; outIdx[row0 + r] = (float)bi;
        atomicAdd(ws + 1 + bi, 1.0f);
        float dist = bv + xnorm;
#pragma unroll
        for (int o = 32; o > 0; o >>= 1) dist += __shfl_down(dist, o, 64);
        if (r == 0) atomicAdd(ws, dist);
    }
    __syncthreads();
#pragma unroll
    for (int it = 0; it < 16; ++it) {
        int f = it * 256 + tid, rr = f >> 6, c4 = f & 63;
        *reinterpret_cast<f32x4*>(outQ + (row0 + rr) * D + c4 * 4) =
            *reinterpret_cast<const f32x4*>(e + fidx[rr] * D + c4 * 4);
    }
}

// ---------------- finalize: loss + perplexity ----------------
__global__ void vq_final_kernel(const float* __restrict__ ws,
                                float* __restrict__ outLoss, float* __restrict__ outPpl,
                                float invN, float invND) {
    int t = threadIdx.x;
    float p = ws[1 + t] * invN;
    float term = p * logf(p + 1e-10f);
#pragma unroll
    for (int o = 32; o > 0; o >>= 1) term += __shfl_down(term, o, 64);
    __shared__ float s[16];
    if ((t & 63) == 0) s[t >> 6] = term;
    __syncthreads();
    if (t == 0) {
        float tot = 0.f;
#pragma unroll
        for (int i = 0; i < 16; ++i) tot += s[i];
        *outPpl  = expf(-tot);
        *outLoss = 1.25f * ws[0] * invND;
    }
}

extern "C" void kernel_launch(void* const* d_in, const int* in_sizes, int n_in,
                              void* d_out, int out_size, void* d_ws, size_t ws_size,
                              hipStream_t stream) {
    const float* x = (const float*)d_in[0];
    const float* e = (const float*)d_in[1];
    const int NX = in_sizes[0];     // N*D = 8388608
    const int N  = NX / D;          // 32768

    float* out     = (float*)d_out;
    float* outQ    = out;
    float* outLoss = out + NX;
    float* outIdx  = out + NX + 1;
    float* outPpl  = out + NX + 1 + N;
    float* ws      = (float*)d_ws;

    if (ws_size >= WS_NEEDED && (N % ROWS) == 0) {
        prep_kernel<<<513, 256, 0, stream>>>(e, ws);   // block 512 zeroes loss+counts
        vq_fused_kernel<<<N / ROWS, 256, 0, stream>>>(x, e, outQ, outIdx, ws);
    } else {
        (void)hipMemsetAsync(d_ws, 0, 4112, stream);
        enorm_kernel<<<M, 64, 0, stream>>>(e, ws + WS_ENORM_F);
        vq_main_kernel<<<N / 64, 256, 0, stream>>>(x, e, outQ, outIdx, ws);
    }
    vq_final_kernel<<<1, 1024, 0, stream>>>(ws, outLoss, outPpl,
                                            1.0f / (float)N, 1.0f / (float)NX);
}